// Round 2
// baseline (227.794 us; speedup 1.0000x reference)
//
#include <hip/hip_runtime.h>
#include <hip/hip_cooperative_groups.h>
#include <cstdint>
#include <cmath>

#define IN_FEATURES 1024
#define OUT_FEATURES 1024
#define NUM_GMM 5
#define ROWS ((IN_FEATURES + 1) * OUT_FEATURES)   // 1049600 = 131072*8 + 1024

struct U2 { uint32_t a, b; };

__host__ __device__ constexpr uint32_t rotl32c(uint32_t x, int d) {
  return (x << d) | (x >> (32 - d));
}

// Exact JAX threefry2x32 (20 rounds, 5 key injections)
#define TF_ROUND(r) { x0 += x1; x1 = rotl32c(x1, (r)); x1 ^= x0; }
__host__ __device__ constexpr U2 threefry2x32(uint32_t k0, uint32_t k1,
                                              uint32_t x0, uint32_t x1) {
  const uint32_t ks0 = k0, ks1 = k1, ks2 = k0 ^ k1 ^ 0x1BD11BDAu;
  x0 += ks0; x1 += ks1;
  TF_ROUND(13) TF_ROUND(15) TF_ROUND(26) TF_ROUND(6)
  x0 += ks1; x1 += ks2 + 1u;
  TF_ROUND(17) TF_ROUND(29) TF_ROUND(16) TF_ROUND(24)
  x0 += ks2; x1 += ks0 + 2u;
  TF_ROUND(13) TF_ROUND(15) TF_ROUND(26) TF_ROUND(6)
  x0 += ks0; x1 += ks1 + 3u;
  TF_ROUND(17) TF_ROUND(29) TF_ROUND(16) TF_ROUND(24)
  x0 += ks1; x1 += ks2 + 4u;
  TF_ROUND(13) TF_ROUND(15) TF_ROUND(26) TF_ROUND(6)
  x0 += ks2; x1 += ks0 + 5u;
  return U2{x0, x1};
}

// jax_threefry_partitionable=True (verified R2)
constexpr U2 KC = threefry2x32(0u, 42u, 0u, 0u);   // kcat
constexpr U2 KN = threefry2x32(0u, 42u, 0u, 1u);   // knorm
constexpr uint32_t KCAT0  = KC.a;
constexpr uint32_t KCAT1  = KC.b;
constexpr uint32_t KNORM0 = KN.a;
constexpr uint32_t KNORM1 = KN.b;

__device__ inline float u01_from_bits(uint32_t bits) {
  return __uint_as_float((bits >> 9) | 0x3F800000u) - 1.0f;
}

// CR-grade f64-lite log (err ~4e-15 rel -> f32 result correctly rounded).
// Only executed on near-tie fallback rows (~0.05%).
__device__ inline float log_f32_acc(float x) {
  uint32_t ix = __float_as_uint(x);
  int e = (int)(ix >> 23) - 127;
  float mf = __uint_as_float((ix & 0x007FFFFFu) | 0x3F800000u); // [1,2)
  if (mf > 1.4142135381698608f) { mf *= 0.5f; e += 1; }         // (0.707,1.414]
  double m = (double)mf;
  double d = m + 1.0;                               // [1.707, 2.414]
  double r = (double)__builtin_amdgcn_rcpf((float)d);
  r = r * (2.0 - d * r);                            // Newton 1: ~1e-12
  r = r * (2.0 - d * r);                            // Newton 2: ~1e-16
  double t = (m - 1.0) * r;                         // |t| <= 0.1716
  double t2 = t * t;
  double p = 1.0 / 15.0;
  p = fma(p, t2, 1.0 / 13.0);
  p = fma(p, t2, 1.0 / 11.0);
  p = fma(p, t2, 1.0 / 9.0);
  p = fma(p, t2, 1.0 / 7.0);
  p = fma(p, t2, 1.0 / 5.0);
  p = fma(p, t2, 1.0 / 3.0);
  p = fma(p, t2, 1.0);
  double res = fma((double)e, 0.693147180559945309417, 2.0 * t * p);
  return (float)res;
}

__device__ inline float u_from_bits_clamped(uint32_t bits) {
  float f = u01_from_bits(bits);
  return fmaxf(1.17549435e-38f, f + 1.17549435e-38f);
}

// Accurate gumbel (CR f32 chain) — fallback path only
__device__ inline float gumbel_acc(uint32_t bits) {
  float u = u_from_bits_clamped(bits);
  float t1 = log_f32_acc(u);
  float t2 = log_f32_acc(-t1);
  return -t2;
}

// Cheap gumbel: hw v_log_f32. abs err <= ~8e-6; values only feed argmax,
// near-ties (margin < 1e-3) re-resolved with gumbel_acc.
__device__ inline float gumbel_fast(uint32_t bits) {
  float u = u_from_bits_clamped(bits);
  float t1 = __logf(u);          // < 0
  return -__logf(-t1);
}

// XLA ErfInv f32 (Giles). log1p(-x^2) -> -log((1-x)(1+x)): cancellation-safe
__device__ inline float erfinv_xla(float x) {
  float s = (1.0f - x) * (1.0f + x);
  float w = -__logf(s);
  float p;
  if (w < 5.0f) {
    w = w - 2.5f;
    p = 2.81022636e-08f;
    p = fmaf(p, w, 3.43273939e-07f);
    p = fmaf(p, w, -3.5233877e-06f);
    p = fmaf(p, w, -4.39150654e-06f);
    p = fmaf(p, w, 0.00021858087f);
    p = fmaf(p, w, -0.00125372503f);
    p = fmaf(p, w, -0.00417768164f);
    p = fmaf(p, w, 0.246640727f);
    p = fmaf(p, w, 1.50140941f);
  } else {
    w = sqrtf(w) - 3.0f;
    p = -0.000200214257f;
    p = fmaf(p, w, 0.000100950558f);
    p = fmaf(p, w, 0.00134934322f);
    p = fmaf(p, w, -0.00367342844f);
    p = fmaf(p, w, 0.00573950773f);
    p = fmaf(p, w, -0.0076224613f);
    p = fmaf(p, w, 0.00943887047f);
    p = fmaf(p, w, 1.00167406f);
    p = fmaf(p, w, 2.83297682f);
  }
  return p * x;
}

__device__ inline float normal_from_bits(uint32_t bits) {
  float f = u01_from_bits(bits);
  const float lo = -0.99999994f;
  float u = fmaxf(lo, f * 2.0f + lo);
  return 1.4142135623730951f * erfinv_xla(u);
}

__device__ inline unsigned short f32_to_bf16_rne(float f) {
  uint32_t u = __float_as_uint(f);
  return (unsigned short)((u + 0x7FFFu + ((u >> 16) & 1u)) >> 16);
}

// ---- prep building blocks (shared by fused + fallback kernels) ----
__device__ inline void load_row5(const float* __restrict__ weight,
                                 const float* __restrict__ mean,
                                 const float* __restrict__ logstd, int r,
                                 float wv[NUM_GMM], float mv[NUM_GMM],
                                 float lv[NUM_GMM]) {
#pragma unroll
  for (int g = 0; g < NUM_GMM; ++g) {
    wv[g] = weight[(size_t)r * NUM_GMM + g];
    mv[g] = mean[(size_t)r * NUM_GMM + g];
    lv[g] = logstd[(size_t)r * NUM_GMM + g];
  }
}

__device__ inline void sample_row(int r, const float wv[NUM_GMM],
                                  const float mv[NUM_GMM],
                                  const float lv[NUM_GMM],
                                  unsigned short* __restrict__ wh,
                                  float* __restrict__ bias_f32) {
  uint32_t bits[NUM_GMM];
  float v[NUM_GMM];
#pragma unroll
  for (int g = 0; g < NUM_GMM; ++g) {
    U2 t = threefry2x32(KCAT0, KCAT1, 0u, (uint32_t)(r * NUM_GMM + g));
    bits[g] = t.a ^ t.b;
    v[g] = gumbel_fast(bits[g]) + wv[g];
  }
  int idx = 0;
  float best = v[0], second = -3.402823466e+38f;
#pragma unroll
  for (int g = 1; g < NUM_GMM; ++g) {
    if (v[g] > best) { second = best; best = v[g]; idx = g; }
    else if (v[g] > second) { second = v[g]; }
  }
  if (__builtin_expect(best - second < 1e-3f, 0)) {  // near-tie: CR re-resolve
    idx = 0;
    best = -3.402823466e+38f;
#pragma unroll
    for (int g = 0; g < NUM_GMM; ++g) {
      float va = gumbel_acc(bits[g]) + wv[g];
      if (va > best) { best = va; idx = g; }   // strict >: first-max (argmax)
    }
  }

  U2 tn = threefry2x32(KNORM0, KNORM1, 0u, (uint32_t)r);
  float eps = normal_from_bits(tn.a ^ tn.b);

  float m = mv[0], l = lv[0];
#pragma unroll
  for (int g = 1; g < NUM_GMM; ++g) {
    bool sel = (idx == g);
    m = sel ? mv[g] : m;
    l = sel ? lv[g] : l;
  }
  float e2 = __expf(2.0f * l);
  float th = 1.0f - 2.0f * __builtin_amdgcn_rcpf(e2 + 1.0f);
  float sd = __expf(3.0f * th);
  float wbv = m + sd * eps;
  wh[r] = f32_to_bf16_rne(wbv);
  if (r < OUT_FEATURES) bias_f32[r] = wbv;
}

__device__ inline void convert_chunk(const float* __restrict__ x,
                                     unsigned short* __restrict__ xh, int c) {
  int i = c * 8;
  float4 a = *(const float4*)(x + i);
  float4 b = *(const float4*)(x + i + 4);
  union { unsigned short s[8]; uint4 v; } o;
  o.s[0] = f32_to_bf16_rne(a.x); o.s[1] = f32_to_bf16_rne(a.y);
  o.s[2] = f32_to_bf16_rne(a.z); o.s[3] = f32_to_bf16_rne(a.w);
  o.s[4] = f32_to_bf16_rne(b.x); o.s[5] = f32_to_bf16_rne(b.y);
  o.s[6] = f32_to_bf16_rne(b.z); o.s[7] = f32_to_bf16_rne(b.w);
  *(uint4*)(xh + i) = o.v;
}

// ---------------- shared GEMM defs ----------------
typedef __attribute__((ext_vector_type(8))) short bf16x8;
typedef __attribute__((ext_vector_type(4))) float f32x4;

#define GBM 128
#define GBN 128
#define GBK 64

__device__ inline void load_lds16(const void* g, void* l) {
  __builtin_amdgcn_global_load_lds(
      (const __attribute__((address_space(1))) unsigned int*)g,
      (__attribute__((address_space(3))) unsigned int*)l, 16, 0, 0);
}

// =====================================================================
// FUSED cooperative kernel: 256 blocks x 512 threads (1 block/CU).
// Phase A: prep spread over 131072 threads (8 rows each + 4 x-chunks),
//          1-row-ahead load pipeline (keep ~8KB/CU vmem in flight).
// grid.sync()
// Phase B: 128x128 gemm tile, 8 waves (2/SIMD) split-K: wave-groups
//          {0-3}/{4-7} take k-subtile s=0/1 of each 64-K step. Per-kt LDS
//          traffic unchanged vs 4-wave (wave tile still 64x64); 2 waves/SIMD
//          gives MFMA<->ds_read cross-wave overlap. Partials combined via
//          LDS scratch at the end.
// =====================================================================
__global__ __launch_bounds__(512, 2) void fused_kernel(
    const float* __restrict__ mean, const float* __restrict__ logstd,
    const float* __restrict__ weight, const float* __restrict__ x,
    unsigned short* __restrict__ wh, float* __restrict__ bias_f32,
    unsigned short* __restrict__ xh, float* __restrict__ out, int n_chunks) {
  // 3 double... triple-buffered tiles: per buf A 16KB + B 16KB => 96 KB
  __shared__ __align__(16) unsigned short smem[3 * 16384];
  const int tid = threadIdx.x;
  const int gt = blockIdx.x * 512 + tid;        // 0..131071

  // ---------------- Phase A ----------------
  // x conversion: chunks gt, gt+131072, ... (n_chunks = 524288)
  for (int c = gt; c < n_chunks; c += 131072) convert_chunk(x, xh, c);

  // rows gt + 131072*j, j=0..7, with 1-ahead prefetch of the 15 row dwords
  {
    float wA[NUM_GMM], mA[NUM_GMM], lA[NUM_GMM];
    float wB[NUM_GMM], mB[NUM_GMM], lB[NUM_GMM];
    load_row5(weight, mean, logstd, gt, wA, mA, lA);
#pragma unroll 1
    for (int j = 0; j < 8; j += 2) {
      int r0 = gt + 131072 * j;
      int r1 = r0 + 131072;
      load_row5(weight, mean, logstd, r1, wB, mB, lB);
      sample_row(r0, wA, mA, lA, wh, bias_f32);
      if (j + 2 < 8)
        load_row5(weight, mean, logstd, r1 + 131072, wA, mA, lA);
      sample_row(r1, wB, mB, lB, wh, bias_f32);
    }
    if (gt < ROWS - 131072 * 8) {               // remainder 1024 rows
      int r = 131072 * 8 + gt;
      load_row5(weight, mean, logstd, r, wA, mA, lA);
      sample_row(r, wA, mA, lA, wh, bias_f32);
    }
  }

  __threadfence();
  cooperative_groups::this_grid().sync();

  // ---------------- Phase B: GEMM ----------------
  const unsigned short* W = wh + OUT_FEATURES;
  const int w = tid >> 6;
  const int L = tid & 63;
  const int s  = w >> 2;        // k-subtile half (split-K)
  const int wr = (w >> 1) & 1;  // row half (64 rows)
  const int wc = w & 1;         // col half (64 cols)

  // XCD-rectangular swizzle (same as R1): 256 tiles = 32m x 8n
  const int lin = blockIdx.x;
  const int xcd = lin & 7;
  const int loc = lin >> 3;
  const int m_tile = ((xcd >> 1) * 8 + (loc >> 2)) * GBM;
  const int n_tile = ((xcd & 1) * 4 + (loc & 3)) * GBN;

  // staging decomposition: thread t -> slots t, t+512 per operand
  const int sm = tid & 15;
  const int sh = (tid >> 4) & 3;
  const int sk = (tid >> 6) & 1;
  const int sb = tid >> 7;          // 0..3
  const int kofs = sk * 32 + sh * 8;

  const unsigned short* gA[2];
  const unsigned short* gB[2];
#pragma unroll
  for (int i = 0; i < 2; ++i) {
    gA[i] = xh + (size_t)(m_tile + (4 * i + sb) * 16 + sm) * IN_FEATURES + kofs;
    gB[i] = W + (size_t)(n_tile + (4 * i + sb) * 16 + sm) * IN_FEATURES + kofs;
  }

  f32x4 acc[4][4];
#pragma unroll
  for (int a = 0; a < 4; ++a)
#pragma unroll
    for (int b = 0; b < 4; ++b) acc[a][b] = (f32x4){0.f, 0.f, 0.f, 0.f};

  // per-buf bases (ushort units): A at buf*16384, B at buf*16384 + 8192
#define ABASE(buf) (smem + (buf) * 16384)
#define BBASE(buf) (smem + (buf) * 16384 + 8192)
#define FSTAGE(buf, k0)                                                      \
  {                                                                          \
    _Pragma("unroll")                                                        \
    for (int i = 0; i < 2; ++i)                                              \
      load_lds16(gA[i] + (k0), ABASE(buf) + (size_t)(tid + 512 * i) * 8);    \
    _Pragma("unroll")                                                        \
    for (int i = 0; i < 2; ++i)                                              \
      load_lds16(gB[i] + (k0), BBASE(buf) + (size_t)(tid + 512 * i) * 8);    \
  }

  FSTAGE(0, 0)
  FSTAGE(1, GBK)

  const int NK = IN_FEATURES / GBK;   // 16
#pragma unroll
  for (int kt = 0; kt < NK; ++kt) {
    // stage-kt complete; stage kt+1's 4 loads may stay in flight.
    // Last iter: nothing younger outstanding -> full drain.
    if (kt < NK - 1) {
      asm volatile("s_waitcnt vmcnt(4)" ::: "memory");
    } else {
      asm volatile("s_waitcnt vmcnt(0)" ::: "memory");
    }
    asm volatile("s_barrier" ::: "memory");
    if (kt + 2 < NK) FSTAGE((kt + 2) % 3, (kt + 2) * GBK)
    const unsigned short* Ab = ABASE(kt % 3);
    const unsigned short* Bb = BBASE(kt % 3);
    bf16x8 a[4], b[4];
#pragma unroll
    for (int m = 0; m < 4; ++m)
      a[m] = *(const bf16x8*)(Ab + (((wr * 4 + m) * 2 + s) * 64 + L) * 8);
#pragma unroll
    for (int n = 0; n < 4; ++n)
      b[n] = *(const bf16x8*)(Bb + (((wc * 4 + n) * 2 + s) * 64 + L) * 8);
#pragma unroll
    for (int m = 0; m < 4; ++m)
#pragma unroll
      for (int n = 0; n < 4; ++n)
        acc[m][n] = __builtin_amdgcn_mfma_f32_16x16x32_bf16(
            a[m], b[n], acc[m][n], 0, 0, 0);
  }

  // ---- split-K combine via LDS scratch (64 KB of the 96 KB) ----
  __syncthreads();                       // all ds_reads/stages drained
  float* sc = (float*)smem;
  if (w >= 4) {
    const int q = w & 3;
#pragma unroll
    for (int m = 0; m < 4; ++m)
#pragma unroll
      for (int n = 0; n < 4; ++n)
        *(f32x4*)(sc + q * 4096 + ((m * 4 + n) * 64 + L) * 4) = acc[m][n];
  }
  __syncthreads();
  if (w < 4) {
    const int q = w & 3;
#pragma unroll
    for (int m = 0; m < 4; ++m)
#pragma unroll
      for (int n = 0; n < 4; ++n) {
        f32x4 o = *(const f32x4*)(sc + q * 4096 + ((m * 4 + n) * 64 + L) * 4);
        acc[m][n] += o;
      }
    // Epilogue: C/D layout col = L&15, row = (L>>4)*4 + reg (m89-verified)
    const int colL = L & 15;
    const int rowq = (L >> 4) * 4;
    float bv[4];
#pragma unroll
    for (int nb = 0; nb < 4; ++nb)
      bv[nb] = bias_f32[n_tile + wc * 64 + nb * 16 + colL];
#pragma unroll
    for (int mb = 0; mb < 4; ++mb) {
#pragma unroll
      for (int reg = 0; reg < 4; ++reg) {
        int row = m_tile + wr * 64 + mb * 16 + rowq + reg;
#pragma unroll
        for (int nb = 0; nb < 4; ++nb) {
          out[(size_t)row * OUT_FEATURES + n_tile + wc * 64 + nb * 16 + colL] =
              acc[mb][nb][reg] + bv[nb];
        }
      }
    }
  }
}

// =====================================================================
// Fallback path (R1 kernels, unchanged) — used if cooperative launch is
// rejected (e.g. graph-capture incompatibility).
// =====================================================================
__global__ __launch_bounds__(256) void prep_kernel(
    const float* __restrict__ mean, const float* __restrict__ logstd,
    const float* __restrict__ weight, const float* __restrict__ x,
    unsigned short* __restrict__ wh, float* __restrict__ bias_f32,
    unsigned short* __restrict__ xh, int n_chunks) {
  const int r = blockIdx.x * 256 + threadIdx.x;
  float wv[NUM_GMM], mv[NUM_GMM], lv[NUM_GMM];
  load_row5(weight, mean, logstd, r, wv, mv, lv);
  if (r < n_chunks) convert_chunk(x, xh, r);
  sample_row(r, wv, mv, lv, wh, bias_f32);
}

__global__ __launch_bounds__(256) void gemm_mfma_kernel(
    const unsigned short* __restrict__ xh, const unsigned short* __restrict__ wh,
    const float* __restrict__ bias, float* __restrict__ out) {
  __shared__ unsigned short As[3][GBM * GBK];
  __shared__ unsigned short Bs[3][GBN * GBK];

  const unsigned short* W = wh + OUT_FEATURES;
  const int tid = threadIdx.x;
  const int w = tid >> 6;
  const int L = tid & 63;
  const int wr = w >> 1;
  const int wc = w & 1;

  const int lin = blockIdx.x;
  const int xcd = lin & 7;
  const int loc = lin >> 3;
  const int m_tile = ((xcd >> 1) * 8 + (loc >> 2)) * GBM;
  const int n_tile = ((xcd & 1) * 4 + (loc & 3)) * GBN;

  const int sm = tid & 15;
  const int sh = (tid >> 4) & 3;
  const int sk = (tid >> 6) & 1;
  const int sb = tid >> 7;
  const int kofs = sk * 32 + sh * 8;

  const unsigned short* gA[4];
  const unsigned short* gB[4];
#pragma unroll
  for (int i = 0; i < 4; ++i)
    gA[i] = xh + (size_t)(m_tile + (2 * i + sb) * 16 + sm) * IN_FEATURES + kofs;
#pragma unroll
  for (int i = 0; i < 4; ++i)
    gB[i] = W + (size_t)(n_tile + (2 * i + sb) * 16 + sm) * IN_FEATURES + kofs;

  f32x4 acc[4][4];
#pragma unroll
  for (int a = 0; a < 4; ++a)
#pragma unroll
    for (int b = 0; b < 4; ++b) acc[a][b] = (f32x4){0.f, 0.f, 0.f, 0.f};

#define STAGE(buf, k0)                                                    \
  {                                                                       \
    _Pragma("unroll")                                                     \
    for (int i = 0; i < 4; ++i)                                           \
      load_lds16(gA[i] + (k0), &As[buf][(size_t)(tid + 256 * i) * 8]);    \
    _Pragma("unroll")                                                     \
    for (int i = 0; i < 4; ++i)                                           \
      load_lds16(gB[i] + (k0), &Bs[buf][(size_t)(tid + 256 * i) * 8]);    \
  }

  STAGE(0, 0)
  STAGE(1, GBK)

  const int NK = IN_FEATURES / GBK;
#pragma unroll
  for (int kt = 0; kt < NK; ++kt) {
    if (kt < NK - 1) {
      asm volatile("s_waitcnt vmcnt(8)" ::: "memory");
    } else {
      asm volatile("s_waitcnt vmcnt(0)" ::: "memory");
    }
    asm volatile("s_barrier" ::: "memory");
    if (kt + 2 < NK) STAGE((kt + 2) % 3, (kt + 2) * GBK)
    const unsigned short* Ab = As[kt % 3];
    const unsigned short* Bb = Bs[kt % 3];
#pragma unroll
    for (int s = 0; s < 2; ++s) {
      bf16x8 a[4], b[4];
#pragma unroll
      for (int m = 0; m < 4; ++m)
        a[m] = *(const bf16x8*)(Ab + (((wr * 4 + m) * 2 + s) * 64 + L) * 8);
#pragma unroll
      for (int n = 0; n < 4; ++n)
        b[n] = *(const bf16x8*)(Bb + (((wc * 4 + n) * 2 + s) * 64 + L) * 8);
#pragma unroll
      for (int m = 0; m < 4; ++m)
#pragma unroll
        for (int n = 0; n < 4; ++n)
          acc[m][n] = __builtin_amdgcn_mfma_f32_16x16x32_bf16(
              a[m], b[n], acc[m][n], 0, 0, 0);
    }
  }

  const int colL = L & 15;
  const int rowq = (L >> 4) * 4;
  float bv[4];
#pragma unroll
  for (int nb = 0; nb < 4; ++nb)
    bv[nb] = bias[n_tile + wc * 64 + nb * 16 + colL];
#pragma unroll
  for (int mb = 0; mb < 4; ++mb) {
#pragma unroll
    for (int reg = 0; reg < 4; ++reg) {
      int row = m_tile + wr * 64 + mb * 16 + rowq + reg;
#pragma unroll
      for (int nb = 0; nb < 4; ++nb) {
        out[(size_t)row * OUT_FEATURES + n_tile + wc * 64 + nb * 16 + colL] =
            acc[mb][nb][reg] + bv[nb];
      }
    }
  }
}

extern "C" void kernel_launch(void* const* d_in, const int* in_sizes, int n_in,
                              void* d_out, int out_size, void* d_ws, size_t ws_size,
                              hipStream_t stream) {
  const float* x      = (const float*)d_in[0];
  const float* mean   = (const float*)d_in[1];
  const float* logstd = (const float*)d_in[2];
  const float* weight = (const float*)d_in[3];
  float* out = (float*)d_out;

  const int M = in_sizes[0] / IN_FEATURES;   // 4096

  // ws layout: xh bf16 [M*1024] | wh bf16 [ROWS] | bias f32 [1024]
  unsigned short* xh = (unsigned short*)d_ws;
  unsigned short* wh = (unsigned short*)((char*)d_ws + (size_t)M * IN_FEATURES * 2);
  float* biasf = (float*)((char*)wh + (size_t)ROWS * 2);

  int n_chunks = M * IN_FEATURES / 8;

  void* args[] = {(void*)&mean, (void*)&logstd, (void*)&weight, (void*)&x,
                  (void*)&wh, (void*)&biasf, (void*)&xh, (void*)&out,
                  (void*)&n_chunks};
  hipError_t e = hipLaunchCooperativeKernel((void*)fused_kernel, dim3(256),
                                            dim3(512), args, 0, stream);
  if (e != hipSuccess) {
    (void)hipGetLastError();   // clear sticky error, fall back to 2-kernel path
    prep_kernel<<<ROWS / 256, 256, 0, stream>>>(
        mean, logstd, weight, x, wh, biasf, xh, n_chunks);
    gemm_mfma_kernel<<<dim3(256), 256, 0, stream>>>(xh, wh, biasf, out);
  }
}

// Round 3
// 131.960 us; speedup vs baseline: 1.7262x; 1.7262x over previous
//
#include <hip/hip_runtime.h>
#include <cstdint>
#include <cmath>

#define IN_FEATURES 1024
#define OUT_FEATURES 1024
#define NUM_GMM 5
#define ROWS ((IN_FEATURES + 1) * OUT_FEATURES)   // 1049600 = 4100*256

struct U2 { uint32_t a, b; };

__host__ __device__ constexpr uint32_t rotl32c(uint32_t x, int d) {
  return (x << d) | (x >> (32 - d));
}

// Exact JAX threefry2x32 (20 rounds, 5 key injections)
#define TF_ROUND(r) { x0 += x1; x1 = rotl32c(x1, (r)); x1 ^= x0; }
__host__ __device__ constexpr U2 threefry2x32(uint32_t k0, uint32_t k1,
                                              uint32_t x0, uint32_t x1) {
  const uint32_t ks0 = k0, ks1 = k1, ks2 = k0 ^ k1 ^ 0x1BD11BDAu;
  x0 += ks0; x1 += ks1;
  TF_ROUND(13) TF_ROUND(15) TF_ROUND(26) TF_ROUND(6)
  x0 += ks1; x1 += ks2 + 1u;
  TF_ROUND(17) TF_ROUND(29) TF_ROUND(16) TF_ROUND(24)
  x0 += ks2; x1 += ks0 + 2u;
  TF_ROUND(13) TF_ROUND(15) TF_ROUND(26) TF_ROUND(6)
  x0 += ks0; x1 += ks1 + 3u;
  TF_ROUND(17) TF_ROUND(29) TF_ROUND(16) TF_ROUND(24)
  x0 += ks1; x1 += ks2 + 4u;
  TF_ROUND(13) TF_ROUND(15) TF_ROUND(26) TF_ROUND(6)
  x0 += ks2; x1 += ks0 + 5u;
  return U2{x0, x1};
}

// jax_threefry_partitionable=True (verified R2)
constexpr U2 KC = threefry2x32(0u, 42u, 0u, 0u);   // kcat
constexpr U2 KN = threefry2x32(0u, 42u, 0u, 1u);   // knorm
constexpr uint32_t KCAT0  = KC.a;
constexpr uint32_t KCAT1  = KC.b;
constexpr uint32_t KNORM0 = KN.a;
constexpr uint32_t KNORM1 = KN.b;

__device__ inline float u01_from_bits(uint32_t bits) {
  return __uint_as_float((bits >> 9) | 0x3F800000u) - 1.0f;
}

// CR-grade f64-lite log (err ~4e-15 rel -> f32 result correctly rounded).
// Only executed on near-tie fallback rows (~0.05%).
__device__ inline float log_f32_acc(float x) {
  uint32_t ix = __float_as_uint(x);
  int e = (int)(ix >> 23) - 127;
  float mf = __uint_as_float((ix & 0x007FFFFFu) | 0x3F800000u); // [1,2)
  if (mf > 1.4142135381698608f) { mf *= 0.5f; e += 1; }         // (0.707,1.414]
  double m = (double)mf;
  double d = m + 1.0;                               // [1.707, 2.414]
  double r = (double)__builtin_amdgcn_rcpf((float)d);
  r = r * (2.0 - d * r);                            // Newton 1: ~1e-12
  r = r * (2.0 - d * r);                            // Newton 2: ~1e-16
  double t = (m - 1.0) * r;                         // |t| <= 0.1716
  double t2 = t * t;
  double p = 1.0 / 15.0;
  p = fma(p, t2, 1.0 / 13.0);
  p = fma(p, t2, 1.0 / 11.0);
  p = fma(p, t2, 1.0 / 9.0);
  p = fma(p, t2, 1.0 / 7.0);
  p = fma(p, t2, 1.0 / 5.0);
  p = fma(p, t2, 1.0 / 3.0);
  p = fma(p, t2, 1.0);
  double res = fma((double)e, 0.693147180559945309417, 2.0 * t * p);
  return (float)res;
}

__device__ inline float u_from_bits_clamped(uint32_t bits) {
  float f = u01_from_bits(bits);
  return fmaxf(1.17549435e-38f, f + 1.17549435e-38f);
}

// Accurate gumbel (CR f32 chain) — fallback path only
__device__ inline float gumbel_acc(uint32_t bits) {
  float u = u_from_bits_clamped(bits);
  float t1 = log_f32_acc(u);
  float t2 = log_f32_acc(-t1);
  return -t2;
}

// Cheap gumbel: hw v_log_f32. abs err <= ~8e-6; values only feed argmax,
// near-ties (margin < 1e-3) re-resolved with gumbel_acc.
__device__ inline float gumbel_fast(uint32_t bits) {
  float u = u_from_bits_clamped(bits);
  float t1 = __logf(u);          // < 0
  return -__logf(-t1);
}

// XLA ErfInv f32 (Giles). log1p(-x^2) -> -log((1-x)(1+x)): cancellation-safe
__device__ inline float erfinv_xla(float x) {
  float s = (1.0f - x) * (1.0f + x);
  float w = -__logf(s);
  float p;
  if (w < 5.0f) {
    w = w - 2.5f;
    p = 2.81022636e-08f;
    p = fmaf(p, w, 3.43273939e-07f);
    p = fmaf(p, w, -3.5233877e-06f);
    p = fmaf(p, w, -4.39150654e-06f);
    p = fmaf(p, w, 0.00021858087f);
    p = fmaf(p, w, -0.00125372503f);
    p = fmaf(p, w, -0.00417768164f);
    p = fmaf(p, w, 0.246640727f);
    p = fmaf(p, w, 1.50140941f);
  } else {
    w = sqrtf(w) - 3.0f;
    p = -0.000200214257f;
    p = fmaf(p, w, 0.000100950558f);
    p = fmaf(p, w, 0.00134934322f);
    p = fmaf(p, w, -0.00367342844f);
    p = fmaf(p, w, 0.00573950773f);
    p = fmaf(p, w, -0.0076224613f);
    p = fmaf(p, w, 0.00943887047f);
    p = fmaf(p, w, 1.00167406f);
    p = fmaf(p, w, 2.83297682f);
  }
  return p * x;
}

__device__ inline float normal_from_bits(uint32_t bits) {
  float f = u01_from_bits(bits);
  const float lo = -0.99999994f;
  float u = fmaxf(lo, f * 2.0f + lo);
  return 1.4142135623730951f * erfinv_xla(u);
}

__device__ inline unsigned short f32_to_bf16_rne(float f) {
  uint32_t u = __float_as_uint(f);
  return (unsigned short)((u + 0x7FFFu + ((u >> 16) & 1u)) >> 16);
}

// ---- prep building blocks ----
__device__ inline void load_row5(const float* __restrict__ weight,
                                 const float* __restrict__ mean,
                                 const float* __restrict__ logstd, int r,
                                 float wv[NUM_GMM], float mv[NUM_GMM],
                                 float lv[NUM_GMM]) {
#pragma unroll
  for (int g = 0; g < NUM_GMM; ++g) {
    wv[g] = weight[(size_t)r * NUM_GMM + g];
    mv[g] = mean[(size_t)r * NUM_GMM + g];
    lv[g] = logstd[(size_t)r * NUM_GMM + g];
  }
}

__device__ inline void sample_row(int r, const float wv[NUM_GMM],
                                  const float mv[NUM_GMM],
                                  const float lv[NUM_GMM],
                                  unsigned short* __restrict__ wh,
                                  float* __restrict__ bias_f32) {
  uint32_t bits[NUM_GMM];
  float v[NUM_GMM];
#pragma unroll
  for (int g = 0; g < NUM_GMM; ++g) {
    U2 t = threefry2x32(KCAT0, KCAT1, 0u, (uint32_t)(r * NUM_GMM + g));
    bits[g] = t.a ^ t.b;
    v[g] = gumbel_fast(bits[g]) + wv[g];
  }
  int idx = 0;
  float best = v[0], second = -3.402823466e+38f;
#pragma unroll
  for (int g = 1; g < NUM_GMM; ++g) {
    if (v[g] > best) { second = best; best = v[g]; idx = g; }
    else if (v[g] > second) { second = v[g]; }
  }
  if (__builtin_expect(best - second < 1e-3f, 0)) {  // near-tie: CR re-resolve
    idx = 0;
    best = -3.402823466e+38f;
#pragma unroll
    for (int g = 0; g < NUM_GMM; ++g) {
      float va = gumbel_acc(bits[g]) + wv[g];
      if (va > best) { best = va; idx = g; }   // strict >: first-max (argmax)
    }
  }

  U2 tn = threefry2x32(KNORM0, KNORM1, 0u, (uint32_t)r);
  float eps = normal_from_bits(tn.a ^ tn.b);

  float m = mv[0], l = lv[0];
#pragma unroll
  for (int g = 1; g < NUM_GMM; ++g) {
    bool sel = (idx == g);
    m = sel ? mv[g] : m;
    l = sel ? lv[g] : l;
  }
  float e2 = __expf(2.0f * l);
  float th = 1.0f - 2.0f * __builtin_amdgcn_rcpf(e2 + 1.0f);
  float sd = __expf(3.0f * th);
  float wbv = m + sd * eps;
  wh[r] = f32_to_bf16_rne(wbv);
  if (r < OUT_FEATURES) bias_f32[r] = wbv;
}

__device__ inline void convert_chunk(const float* __restrict__ x,
                                     unsigned short* __restrict__ xh, int c) {
  int i = c * 8;
  float4 a = *(const float4*)(x + i);
  float4 b = *(const float4*)(x + i + 4);
  union { unsigned short s[8]; uint4 v; } o;
  o.s[0] = f32_to_bf16_rne(a.x); o.s[1] = f32_to_bf16_rne(a.y);
  o.s[2] = f32_to_bf16_rne(a.z); o.s[3] = f32_to_bf16_rne(a.w);
  o.s[4] = f32_to_bf16_rne(b.x); o.s[5] = f32_to_bf16_rne(b.y);
  o.s[6] = f32_to_bf16_rne(b.z); o.s[7] = f32_to_bf16_rne(b.w);
  *(uint4*)(xh + i) = o.v;
}

// prep: 4100 blocks x 256 threads — high occupancy (streaming/latency phase
// needs TLP; R2 proved fusing it into a 96KB-LDS kernel collapses it 5x).
__global__ __launch_bounds__(256) void prep_kernel(
    const float* __restrict__ mean, const float* __restrict__ logstd,
    const float* __restrict__ weight, const float* __restrict__ x,
    unsigned short* __restrict__ wh, float* __restrict__ bias_f32,
    unsigned short* __restrict__ xh, int n_chunks) {
  const int r = blockIdx.x * 256 + threadIdx.x;
  float wv[NUM_GMM], mv[NUM_GMM], lv[NUM_GMM];
  load_row5(weight, mean, logstd, r, wv, mv, lv);
  if (r < n_chunks) convert_chunk(x, xh, r);
  sample_row(r, wv, mv, lv, wh, bias_f32);
}

// ---------------- MFMA GEMM: out[M,1024] = xh @ W'^T + bias ----------------
// R3: standalone 512-thread split-K gemm (phase-B of R2's fused kernel,
// which passed): 128x128 tile, 8 waves = 2/SIMD; wave-groups {0-3}/{4-7}
// take k-subtile s=0/1 of each 64-wide K step. Per-CU-kt LDS read traffic
// unchanged (64 KB) but issued by 2 waves/SIMD -> ds_read latency and
// barrier drains overlap the other wave's MFMAs (m114). Partials combined
// through LDS scratch. 96 KB LDS => 1 block/CU; grid 256 = 1 tile/CU.
typedef __attribute__((ext_vector_type(8))) short bf16x8;
typedef __attribute__((ext_vector_type(4))) float f32x4;

#define GBM 128
#define GBN 128
#define GBK 64

__device__ inline void load_lds16(const void* g, void* l) {
  __builtin_amdgcn_global_load_lds(
      (const __attribute__((address_space(1))) unsigned int*)g,
      (__attribute__((address_space(3))) unsigned int*)l, 16, 0, 0);
}

__global__ __launch_bounds__(512) void gemm_mfma_kernel(
    const unsigned short* __restrict__ xh, const unsigned short* __restrict__ wh,
    const float* __restrict__ bias, float* __restrict__ out) {
  // 3 bufs x (A 16 KB + B 16 KB) = 96 KB
  __shared__ __align__(16) unsigned short smem[3 * 16384];

  const unsigned short* W = wh + OUT_FEATURES;
  const int tid = threadIdx.x;
  const int w = tid >> 6;
  const int L = tid & 63;
  const int s  = w >> 2;        // k-subtile half (split-K)
  const int wr = (w >> 1) & 1;  // row half (64 rows)
  const int wc = w & 1;         // col half (64 cols)

  // XCD-rectangular swizzle: 256 tiles = 32m x 8n; XCD x covers
  // m-tiles [(x>>1)*8,+8) x n-tiles [(x&1)*4,+4) -> A 2MB + B 1MB per L2.
  const int lin = blockIdx.x;
  const int xcd = lin & 7;
  const int loc = lin >> 3;
  const int m_tile = ((xcd >> 1) * 8 + (loc >> 2)) * GBM;
  const int n_tile = ((xcd & 1) * 4 + (loc & 3)) * GBN;

  // staging decomposition: thread t -> slots t, t+512 per operand
  const int sm = tid & 15;           // row within 16-block
  const int sh = (tid >> 4) & 3;     // k-chunk (8 elems)
  const int sk = (tid >> 6) & 1;     // k-subtile (0/1)
  const int sb = tid >> 7;           // block parity (0..3)
  const int kofs = sk * 32 + sh * 8;

  const unsigned short* gA[2];
  const unsigned short* gB[2];
#pragma unroll
  for (int i = 0; i < 2; ++i) {
    gA[i] = xh + (size_t)(m_tile + (4 * i + sb) * 16 + sm) * IN_FEATURES + kofs;
    gB[i] = W + (size_t)(n_tile + (4 * i + sb) * 16 + sm) * IN_FEATURES + kofs;
  }

  f32x4 acc[4][4];
#pragma unroll
  for (int a = 0; a < 4; ++a)
#pragma unroll
    for (int b = 0; b < 4; ++b) acc[a][b] = (f32x4){0.f, 0.f, 0.f, 0.f};

#define ABASE(buf) (smem + (buf) * 16384)
#define BBASE(buf) (smem + (buf) * 16384 + 8192)
#define FSTAGE(buf, k0)                                                      \
  {                                                                          \
    _Pragma("unroll")                                                        \
    for (int i = 0; i < 2; ++i)                                              \
      load_lds16(gA[i] + (k0), ABASE(buf) + (size_t)(tid + 512 * i) * 8);    \
    _Pragma("unroll")                                                        \
    for (int i = 0; i < 2; ++i)                                              \
      load_lds16(gB[i] + (k0), BBASE(buf) + (size_t)(tid + 512 * i) * 8);    \
  }

  FSTAGE(0, 0)
  FSTAGE(1, GBK)

  const int NK = IN_FEATURES / GBK;   // 16
#pragma unroll
  for (int kt = 0; kt < NK; ++kt) {
    // stage-kt complete; stage kt+1's 4 loads may stay in flight.
    // Last iter: nothing younger outstanding -> full drain.
    if (kt < NK - 1) {
      asm volatile("s_waitcnt vmcnt(4)" ::: "memory");
    } else {
      asm volatile("s_waitcnt vmcnt(0)" ::: "memory");
    }
    asm volatile("s_barrier" ::: "memory");
    if (kt + 2 < NK) FSTAGE((kt + 2) % 3, (kt + 2) * GBK)
    const unsigned short* Ab = ABASE(kt % 3);
    const unsigned short* Bb = BBASE(kt % 3);
    bf16x8 a[4], b[4];
#pragma unroll
    for (int m = 0; m < 4; ++m)
      a[m] = *(const bf16x8*)(Ab + (((wr * 4 + m) * 2 + s) * 64 + L) * 8);
#pragma unroll
    for (int n = 0; n < 4; ++n)
      b[n] = *(const bf16x8*)(Bb + (((wc * 4 + n) * 2 + s) * 64 + L) * 8);
#pragma unroll
    for (int m = 0; m < 4; ++m)
#pragma unroll
      for (int n = 0; n < 4; ++n)
        acc[m][n] = __builtin_amdgcn_mfma_f32_16x16x32_bf16(
            a[m], b[n], acc[m][n], 0, 0, 0);
  }

  // ---- split-K combine via LDS scratch (64 KB of the 96 KB) ----
  __syncthreads();                       // all ds_reads/stages drained
  float* sc = (float*)smem;
  if (w >= 4) {
    const int q = w & 3;
#pragma unroll
    for (int m = 0; m < 4; ++m)
#pragma unroll
      for (int n = 0; n < 4; ++n)
        *(f32x4*)(sc + q * 4096 + ((m * 4 + n) * 64 + L) * 4) = acc[m][n];
  }
  __syncthreads();
  if (w < 4) {
    const int q = w & 3;
#pragma unroll
    for (int m = 0; m < 4; ++m)
#pragma unroll
      for (int n = 0; n < 4; ++n) {
        f32x4 o = *(const f32x4*)(sc + q * 4096 + ((m * 4 + n) * 64 + L) * 4);
        acc[m][n] += o;
      }
    // Epilogue: C/D layout col = L&15, row = (L>>4)*4 + reg (m89-verified)
    const int colL = L & 15;
    const int rowq = (L >> 4) * 4;
    float bv[4];
#pragma unroll
    for (int nb = 0; nb < 4; ++nb)
      bv[nb] = bias[n_tile + wc * 64 + nb * 16 + colL];
#pragma unroll
    for (int mb = 0; mb < 4; ++mb) {
#pragma unroll
      for (int reg = 0; reg < 4; ++reg) {
        int row = m_tile + wr * 64 + mb * 16 + rowq + reg;
#pragma unroll
        for (int nb = 0; nb < 4; ++nb) {
          out[(size_t)row * OUT_FEATURES + n_tile + wc * 64 + nb * 16 + colL] =
              acc[mb][nb][reg] + bv[nb];
        }
      }
    }
  }
}

extern "C" void kernel_launch(void* const* d_in, const int* in_sizes, int n_in,
                              void* d_out, int out_size, void* d_ws, size_t ws_size,
                              hipStream_t stream) {
  const float* x      = (const float*)d_in[0];
  const float* mean   = (const float*)d_in[1];
  const float* logstd = (const float*)d_in[2];
  const float* weight = (const float*)d_in[3];
  float* out = (float*)d_out;

  const int M = in_sizes[0] / IN_FEATURES;   // 4096

  // ws layout: xh bf16 [M*1024] | wh bf16 [ROWS] | bias f32 [1024]
  unsigned short* xh = (unsigned short*)d_ws;
  unsigned short* wh = (unsigned short*)((char*)d_ws + (size_t)M * IN_FEATURES * 2);
  float* biasf = (float*)((char*)wh + (size_t)ROWS * 2);

  const int n_chunks = M * IN_FEATURES / 8;
  prep_kernel<<<ROWS / 256, 256, 0, stream>>>(
      mean, logstd, weight, x, wh, biasf, xh, n_chunks);

  gemm_mfma_kernel<<<dim3(256), 512, 0, stream>>>(xh, wh, biasf, out);
}